// Round 9
// baseline (419.282 us; speedup 1.0000x reference)
//
#include <hip/hip_runtime.h>
#include <stdint.h>

// WL refinement step: hash rows -> tile-sorted edge binning (LDS counting-sort
// per 16K-edge tile, wave-shfl scan, coalesced flush) -> per-bucket LDS
// multiset accumulation (single commutative u64 sum, srcpart-windowed lab
// gathers) with fused node-hash + hash-table insert -> SINGLE-PASS tail
// (decoupled-lookback scan + relabel gather fused). int64 wraps (JAX).
//
// R9 (post-mortem R8): occupancy x2 at 70% moved accum only -5% -> latency
// theory dead; per-CU serialized line-fetch floor (~0.18 lines/cy, ~64
// outstanding misses). Discriminator this round: volatile (sc0) lab gather
// bypasses vL1D -- if flat, accum is closed permanently.
// Geometry reverted to R7 (best total 405; ncl=980 keeps scatter runs long).
// Tail: k_lookup_scan+k_scan2+k_final fused into one ticket-ordered
// decoupled-lookback kernel; incl/done published via device-scope atomics
// (cross-XCD coherent, no fence subtleties); spins only on lower tickets
// (rep <= i => rb <= bid) so no circular wait.

#define KC1 6364136223846793005ULL
#define KC2 1442695040888963407ULL
#define KC3 2862933555777941757ULL
#define KC4 3202034522624059733ULL
#define KPT 1000003ULL

#define TBL_BITS 21
#define TBL (1u << TBL_BITS)
#define TMASK (TBL - 1u)
#define KEMPTY 0xFFFFFFFFFFFFFFFFULL
#define SIGMASK 0xFFFFFFFFFFF00000ULL   // high 44 bits = signature, low 20 = node idx

// binning: 4096 nodes per bucket (dl=12 bits, src=20 bits -> 32-bit record)
#define BK_SHIFT 12
#define BK_NODES 4096
#define NBK_MAX 256
// 8 block-partitions (blockIdx&7, write privacy) x 4 src-range partitions
// (accum gather window = 2MB of lab). cell = (bk << 2) | sp.
#define NPARTX 8
#define NPARTS 4
#define NPARTS_LOG 2
// per (part,cell) capacity: n=2M p=1/980 -> mean 2041, sigma ~45; ~4K total
// spills expected -> exact ovf path (verified absmax=0 in R3..R8).
#define PCAP 2132u
#define OVFCAP 32768u

// scatter tile: 16384 records staged in LDS, 16 records/thread in registers
#define TILE 16384
#define SUBP 4           // sub-passes of 4096 records (1024 thr x 4)

#define ST_INV 0xFFFFFFFFFFFFFFFFULL

typedef int iv4 __attribute__((ext_vector_type(4)));

__device__ __forceinline__ uint64_t mix64(uint64_t h, uint64_t a, uint64_t b) {
    h *= a;
    h ^= (uint64_t)(((int64_t)h) >> 31);   // arithmetic shift, like jnp int64
    h *= b;
    h ^= (uint64_t)(((int64_t)h) >> 29);
    return h;
}

__device__ __forceinline__ uint32_t tslot(uint64_t k) {
    return (uint32_t)((k * 0x9E3779B97F4A7C15ULL) >> (64 - TBL_BITS));
}

// src-partition via magic-mul division: p = (src * M) >> 38, clamped.
__device__ __forceinline__ uint32_t psel(uint32_t src, uint32_t M) {
    uint32_t p = (uint32_t)(((uint64_t)src * (uint64_t)M) >> 38);
    return p < (NPARTS - 1) ? p : (NPARTS - 1);
}

// 1. lab[i] = mix(poly(x[i,:]), C1, C2); row read as 2x int4
__global__ void k_lab(const int* __restrict__ x, uint64_t* __restrict__ lab, int N, int F) {
    int i = blockIdx.x * blockDim.x + threadIdx.x;
    if (i >= N) return;
    uint64_t l = 0;
    if (F == 8) {
        const iv4* p = (const iv4*)(x + (size_t)i * 8);
        iv4 a = p[0], b = p[1];
        l = (uint64_t)(int64_t)a.x;
        l = l * KPT + (uint64_t)(int64_t)a.y;
        l = l * KPT + (uint64_t)(int64_t)a.z;
        l = l * KPT + (uint64_t)(int64_t)a.w;
        l = l * KPT + (uint64_t)(int64_t)b.x;
        l = l * KPT + (uint64_t)(int64_t)b.y;
        l = l * KPT + (uint64_t)(int64_t)b.z;
        l = l * KPT + (uint64_t)(int64_t)b.w;
    } else {
        const int* row = x + (size_t)i * (size_t)F;
        for (int j = 0; j < F; ++j) l = l * KPT + (uint64_t)(int64_t)row[j];
    }
    lab[i] = mix64(l, KC1, KC2);
}

// 2a. tile-sorted binning. Per 16K-edge tile: LDS hist -> wave-shfl scan ->
//     per-cell global reservation -> cell-sorted LDS stage -> coalesced
//     flush. Requires ncl = NPARTS*NBK <= 1024 (true for N <= 1,048,576).
__global__ __launch_bounds__(1024)
void k_scatter(const int* __restrict__ ei, uint32_t* __restrict__ binned,
               uint32_t* __restrict__ cursor, unsigned long long* __restrict__ ovf,
               unsigned int* __restrict__ ovf_cnt, int E, int NBK, int chunk,
               uint32_t M) {
    __shared__ uint32_t stageRec[TILE];                 // 64 KB
    __shared__ unsigned short stageCell[TILE];          // 32 KB
    __shared__ uint32_t hist[NPARTS * NBK_MAX];         // 4 KB
    __shared__ uint32_t cstart[NPARTS * NBK_MAX];       // 4 KB
    __shared__ uint32_t lbrun[NPARTS * NBK_MAX];        // 4 KB
    __shared__ uint32_t wsum[16];                       // -> ~108 KB total
    const int ncl = NPARTS * NBK;                       // 980; <= 1024 required
    const int part = blockIdx.x & (NPARTX - 1);
    const int tid = threadIdx.x;
    const int lane = tid & 63;
    const int wid = tid >> 6;
    const int b0 = blockIdx.x * chunk;
    const int b1 = min(E, b0 + chunk);
    if (b0 >= b1) return;

    if (tid < ncl) hist[tid] = 0;
    __syncthreads();

    for (int tb = b0; tb < b1; tb += TILE) {
        const int tE = min(TILE, b1 - tb);
        const int lim = min(b1, tb + TILE);
        // ---- 1. load up to 16 edges/thread (compile-time reg indices),
        //         count cells. meta = (cell<<14)|pos, sentinel ~0u.
        uint32_t rc[SUBP * 4];
        uint32_t meta[SUBP * 4];
#pragma unroll
        for (int sidx = 0; sidx < SUBP; ++sidx) {
            const int base = tb + sidx * 4096 + tid * 4;
            int ss[4], dd[4];
            int m = 0;
            if (base + 4 <= lim) {
                iv4 s4 = __builtin_nontemporal_load((const iv4*)(ei + base));
                iv4 d4 = __builtin_nontemporal_load((const iv4*)(ei + (size_t)E + base));
                ss[0]=s4.x; ss[1]=s4.y; ss[2]=s4.z; ss[3]=s4.w;
                dd[0]=d4.x; dd[1]=d4.y; dd[2]=d4.z; dd[3]=d4.w;
                m = 4;
            } else {
                int r = lim - base;
                m = r > 0 ? (r < 4 ? r : 4) : 0;
                for (int j = 0; j < m; ++j) {
                    ss[j] = ei[base + j];
                    dd[j] = ei[(size_t)E + base + j];
                }
            }
#pragma unroll
            for (int j = 0; j < 4; ++j) {
                const int k = sidx * 4 + j;
                if (j < m) {
                    uint32_t bk = (uint32_t)dd[j] >> BK_SHIFT;
                    uint32_t cell = (bk << NPARTS_LOG) | psel((uint32_t)ss[j], M);
                    uint32_t pos = atomicAdd(&hist[cell], 1u);
                    rc[k] = ((uint32_t)(dd[j] & (BK_NODES - 1)) << 20) | (uint32_t)ss[j];
                    meta[k] = (cell << 14) | pos;      // pos < 16384
                } else {
                    meta[k] = 0xFFFFFFFFu;
                }
            }
        }
        __syncthreads();
        // ---- 2. wave-shfl exclusive scan of hist (2 barriers, not 20)
        uint32_t v = (tid < ncl) ? hist[tid] : 0u;
        uint32_t s = v;
#pragma unroll
        for (int off = 1; off < 64; off <<= 1) {
            uint32_t t = __shfl_up(s, off, 64);
            if (lane >= off) s += t;
        }
        if (lane == 63) wsum[wid] = s;
        __syncthreads();
        if (wid == 0) {
            uint32_t w = (lane < 16) ? wsum[lane] : 0u;
#pragma unroll
            for (int off = 1; off < 16; off <<= 1) {
                uint32_t t = __shfl_up(w, off, 64);
                if (lane >= off) w += t;
            }
            if (lane < 16) wsum[lane] = w;   // inclusive scan of wave sums
        }
        __syncthreads();
        uint32_t incl = s + ((wid > 0) ? wsum[wid - 1] : 0u);
        // ---- 3. exclusive fixup + per-cell global reservation
        if (tid < ncl) {
            cstart[tid] = incl - v;
            lbrun[tid] = v ? atomicAdd(&cursor[part * ncl + tid], v) : 0u;
        }
        __syncthreads();
        // ---- 4. stage records sorted by cell
#pragma unroll
        for (int k = 0; k < SUBP * 4; ++k) {
            if (meta[k] != 0xFFFFFFFFu) {
                uint32_t cell = meta[k] >> 14;
                uint32_t p = cstart[cell] + (meta[k] & 0x3FFFu);
                stageRec[p] = rc[k];
                stageCell[p] = (unsigned short)cell;
            }
        }
        __syncthreads();
        // ---- 5. coalesced flush (lane-adjacent i -> contiguous per-cell runs)
        for (int i = tid; i < tE; i += 1024) {
            uint32_t rec = stageRec[i];
            uint32_t c = stageCell[i];
            uint32_t idx = lbrun[c] + ((uint32_t)i - cstart[c]);
            if (idx < PCAP) {
                binned[((size_t)part * ncl + c) * PCAP + idx] = rec;
            } else {
                unsigned int o = atomicAdd(ovf_cnt, 1u);
                if (o < OVFCAP) ovf[o] = ((unsigned long long)(c >> NPARTS_LOG) << 32) | rec;
            }
        }
        if (tid < ncl) hist[tid] = 0;   // ready for next tile
        __syncthreads();
    }
}

// 2b. per-bucket LDS multiset accumulation; sp-outer loop keeps the lab
//     gather window 2MB (L2-resident). ONE u64 LDS atomic/edge. R4/R7 loop
//     shape; lab gathers via volatile (sc0) -> vL1D bypass discriminator.
__global__ __launch_bounds__(1024)
void k_accum(const uint32_t* __restrict__ binned, const uint32_t* __restrict__ cursor,
             const unsigned long long* __restrict__ ovf, const unsigned int* __restrict__ ovf_cnt,
             const uint64_t* __restrict__ lab, unsigned long long* __restrict__ table,
             uint32_t* __restrict__ slot32, int N, int NBK) {
    __shared__ unsigned long long s1[BK_NODES];
    const int ncl = NPARTS * NBK;
    const volatile uint64_t* vlab = (const volatile uint64_t*)lab;
    int b = blockIdx.x;
    for (int t = threadIdx.x; t < BK_NODES; t += blockDim.x) s1[t] = 0ULL;
    __syncthreads();
    for (int sp = 0; sp < NPARTS; ++sp) {
        const uint32_t cell = ((uint32_t)b << NPARTS_LOG) | (uint32_t)sp;
        for (int xp = 0; xp < NPARTX; ++xp) {
            size_t cidx = (size_t)xp * ncl + cell;
            uint32_t cnt = cursor[cidx];
            if (cnt > PCAP) cnt = PCAP;
            const uint32_t* seg = binned + cidx * PCAP;
            for (uint32_t i = threadIdx.x * 4; i < cnt; i += blockDim.x * 4) {
                uint32_t recs[4];
                int m;
                if (i + 4 <= cnt) {
                    iv4 r4 = __builtin_nontemporal_load((const iv4*)(seg + i));
                    recs[0]=(uint32_t)r4.x; recs[1]=(uint32_t)r4.y;
                    recs[2]=(uint32_t)r4.z; recs[3]=(uint32_t)r4.w;
                    m = 4;
                } else {
                    m = (int)(cnt - i);
                    for (int j = 0; j < m; ++j) recs[j] = seg[i + j];
                }
                for (int j = 0; j < m; ++j) {
                    uint64_t nl = vlab[recs[j] & 0xFFFFFu];
                    uint32_t dl = recs[j] >> 20;
                    atomicAdd(&s1[dl], (unsigned long long)mix64(nl, KC1, KC2));
                }
            }
        }
    }
    // overflow sweep (expected ~4K records total; exact correctness backstop)
    uint32_t oc = *ovf_cnt;
    if (oc > OVFCAP) oc = OVFCAP;
    for (uint32_t i = threadIdx.x; i < oc; i += blockDim.x) {
        unsigned long long r = ovf[i];
        if ((uint32_t)(r >> 32) == (uint32_t)b) {
            uint32_t rec = (uint32_t)r;
            uint64_t nl = lab[rec & 0xFFFFFu];
            uint32_t dl = rec >> 20;
            atomicAdd(&s1[dl], (unsigned long long)mix64(nl, KC1, KC2));
        }
    }
    __syncthreads();
    int node0 = b << BK_SHIFT;
    for (int t = threadIdx.x; t < BK_NODES; t += blockDim.x) {
        int node = node0 + t;
        if (node < N) {
            uint64_t l = lab[node];
            uint64_t s = (uint64_t)s1[t];
            // commutative-multiset combine; induces the reference partition
            uint64_t h = mix64(l * KC3 + s, KC1, KC2) ^ mix64(s + l, KC3, KC4);
            // ---- fused insert: claim slot or min-merge into same-sig slot
            uint64_t entry = (h & SIGMASK) | (uint64_t)(uint32_t)node;
            uint32_t slot = tslot(h);
            for (;;) {
                unsigned long long cur = table[slot];
                if (cur == KEMPTY) {
                    unsigned long long prev =
                        atomicCAS(&table[slot], KEMPTY, (unsigned long long)entry);
                    if (prev == KEMPTY) break;
                    cur = prev;   // lost race: resolve with the true value
                }
                if ((cur & SIGMASK) == (entry & SIGMASK)) {
                    atomicMin(&table[slot], (unsigned long long)entry);
                    break;
                }
                slot = (slot + 1u) & TMASK;
            }
            slot32[node] = slot;
        }
    }
}

// 4. FUSED tail: probe-free lookup + single-pass decoupled-lookback scan of
//    first-appearance flags + relabel gather. Ticket-ordered blocks; state[b]
//    publishes {aggregate|inclusive}; incl/done via device-scope atomics
//    (cross-XCD coherent). rep r <= i => rb <= bid (lower ticket) -> spins
//    only on blocks guaranteed resident-or-done: no circular wait.
__global__ __launch_bounds__(1024)
void k_tail(const uint32_t* __restrict__ slot32, const unsigned long long* __restrict__ table,
            int* __restrict__ incl, unsigned long long* __restrict__ state,
            unsigned int* __restrict__ done, unsigned int* __restrict__ ticket,
            int* __restrict__ out, int N) {
    __shared__ int wsum[16];
    __shared__ unsigned int bid_s;
    __shared__ int pfx_s;
    __shared__ int incl_s[1024];
    const int tid = threadIdx.x;
    const int lane = tid & 63;
    const int wid = tid >> 6;
    if (tid == 0) bid_s = atomicAdd(ticket, 1u);
    __syncthreads();
    const int bid = (int)bid_s;
    const int i = bid * 1024 + tid;
    unsigned int r = 0u;
    int v = 0;
    if (i < N) {
        unsigned long long e = table[slot32[i]];
        r = (unsigned int)(e & 0xFFFFFu);
        v = (r == (unsigned int)i) ? 1 : 0;
    }
    // block-wide inclusive scan of flags (wave shfl + 16-wave combine)
    int s = v;
#pragma unroll
    for (int off = 1; off < 64; off <<= 1) {
        int t = __shfl_up(s, off, 64);
        if (lane >= off) s += t;
    }
    if (lane == 63) wsum[wid] = s;
    __syncthreads();
    if (wid == 0) {
        int w = (lane < 16) ? wsum[lane] : 0;
#pragma unroll
        for (int off = 1; off < 16; off <<= 1) {
            int t = __shfl_up(w, off, 64);
            if (lane >= off) w += t;
        }
        if (lane < 16) wsum[lane] = w;   // inclusive scan of wave sums
    }
    __syncthreads();
    const int linc = s + ((wid > 0) ? wsum[wid - 1] : 0);
    const int btot = wsum[15];
    if (tid == 0) {
        if (bid == 0) {
            pfx_s = 0;
            atomicExch(&state[0], (2ULL << 62) | (unsigned long long)(unsigned int)btot);
        } else {
            atomicExch(&state[bid], (1ULL << 62) | (unsigned long long)(unsigned int)btot);
        }
    }
    __syncthreads();
    // decoupled lookback (wave 0), 64-predecessor windows
    if (bid > 0 && wid == 0) {
        int pfx = 0;
        int look = bid - 1;
        for (;;) {
            int idx = look - lane;
            unsigned long long sv = (idx >= 0) ? atomicAdd(&state[idx], 0ULL) : 0ULL;
            bool valid = (idx < 0) || (sv != ST_INV);
            if (__ballot(valid) != ~0ULL) continue;        // predecessor not published yet
            unsigned long long inc_mask = __ballot(idx >= 0 && (sv >> 62) == 2ULL);
            int c;
            if (inc_mask) {
                int L = __ffsll((unsigned long long)inc_mask) - 1;  // nearest inclusive
                c = (idx >= 0 && lane <= L) ? (int)(unsigned int)(sv & 0xFFFFFFFFULL) : 0;
#pragma unroll
                for (int o = 32; o; o >>= 1) c += __shfl_down(c, o, 64);
                pfx += __shfl(c, 0, 64);
                break;
            } else {
                c = (idx >= 0) ? (int)(unsigned int)(sv & 0xFFFFFFFFULL) : 0;
#pragma unroll
                for (int o = 32; o; o >>= 1) c += __shfl_down(c, o, 64);
                pfx += __shfl(c, 0, 64);
                look -= 64;                                 // block 0 is inclusive -> terminates
            }
        }
        if (lane == 0) {
            pfx_s = pfx;
            atomicExch(&state[bid], (2ULL << 62) | (unsigned long long)(unsigned int)(pfx + btot));
        }
    }
    __syncthreads();
    const int gincl = pfx_s + linc;
    incl_s[tid] = gincl;
    if (i < N) (void)atomicExch(&incl[i], gincl);   // device-scope publish
    __syncthreads();                                // barrier drains all waves' vmem
    if (tid == 0) atomicExch(&done[bid], 1u);
    // relabel: out[i] = (#reps <= rep[i]) - 1; rep[i] <= i so rb <= bid
    if (i < N) {
        int rb = (int)(r >> 10);
        int ri;
        if (rb == bid) {
            ri = incl_s[r & 1023u];
        } else {
            while (atomicAdd(&done[rb], 0u) == 0u) {}
            ri = atomicAdd(&incl[r], 0);            // device-scope coherent read
        }
        out[i] = ri - 1;
    }
}

extern "C" void kernel_launch(void* const* d_in, const int* in_sizes, int n_in,
                              void* d_out, int out_size, void* d_ws, size_t ws_size,
                              hipStream_t stream) {
    const int* x  = (const int*)d_in[0];
    const int* ei = (const int*)d_in[1];
    int N = out_size;
    int F = in_sizes[0] / N;
    int E = in_sizes[1] / 2;
    int* out = (int*)d_out;

    int NBK = (N + BK_NODES - 1) >> BK_SHIFT;  // 245 for N=1e6
    uint32_t PSZ = (uint32_t)((N + NPARTS - 1) / NPARTS);         // 250000
    uint32_t M = (uint32_t)(((1ULL << 38) + PSZ - 1) / PSZ);      // magic for /PSZ

    // workspace layout; ~95.2 MB total (<= 96.03 MB proven)
    char* w = (char*)d_ws;
    uint64_t* lab = (uint64_t*)w;                        w += (size_t)N * 8;       // 8 MB
    uint32_t* slot32 = (uint32_t*)w;                     w += (size_t)N * 4;       // 4 MB
    uint32_t* cursor = (uint32_t*)w;                     w += (size_t)NPARTX * NPARTS * NBK_MAX * 4; // 32 KB
    unsigned int* ovf_cnt = (unsigned int*)w;            w += 16;
    unsigned long long* ovf = (unsigned long long*)w;    w += (size_t)OVFCAP * 8;  // 256 KB
    unsigned long long* table = (unsigned long long*)w;  w += (size_t)TBL * 8;     // 16 MB (live thru tail)
    uint32_t* binned = (uint32_t*)w;                     // 8*980*PCAP*4 (~66.9 MB)
    // tail scratch dead until after k_accum -> alias the binned region
    char* a = (char*)binned;
    unsigned long long* state = (unsigned long long*)a;  a += 1024 * 8;   // lookback state
    unsigned int* done = (unsigned int*)a;               a += 1024 * 4;   // per-block done flags
    unsigned int* ticket = (unsigned int*)a;             a += 16;
    int* incl = (int*)a;                                 a += (size_t)N * 4;

    int nb = (N + 255) / 256;
    int NB = (N + 1023) / 1024;
    int SCB = 256;                                // 1 block/CU, part = blockIdx&7
    int chunk = ((E + SCB - 1) / SCB + 3) & ~3;   // 62500 for E=16M

    (void)hipMemsetAsync(cursor, 0, (size_t)NPARTX * NPARTS * NBK_MAX * 4 + 16, stream);
    (void)hipMemsetAsync(table, 0xFF, (size_t)TBL * 8, stream);
    k_lab<<<nb, 256, 0, stream>>>(x, lab, N, F);
    k_scatter<<<SCB, 1024, 0, stream>>>(ei, binned, cursor, ovf, ovf_cnt, E, NBK, chunk, M);
    k_accum<<<NBK, 1024, 0, stream>>>(binned, cursor, ovf, ovf_cnt, lab, table, slot32, N, NBK);
    // tail scratch init (aliases binned -> must be enqueued after k_accum)
    (void)hipMemsetAsync(state, 0xFF, 1024 * 8, stream);
    (void)hipMemsetAsync(done, 0, 1024 * 4 + 16, stream);
    k_tail<<<NB, 1024, 0, stream>>>(slot32, table, incl, state, done, ticket, out, N);
}

// Round 10
// 402.123 us; speedup vs baseline: 1.0427x; 1.0427x over previous
//
#include <hip/hip_runtime.h>
#include <stdint.h>

// WL refinement step: (lab-hash fused) tile-sorted edge binning -> per-bucket
// LDS multiset accumulation (single commutative u64 sum, srcpart-windowed lab
// gathers) with fused node-hash + hash-table insert -> probe-free lookup ->
// first-appearance contiguous relabel (block-sum scan folded into final).
//
// R10 = consolidation (post-mortem R9): sc0 bypass flat -> accum CLOSED at
// ~150us per-CU line-fetch floor (invariant to occupancy x2, ILP x4, lane
// activity x2, L1 path). Fused-atomic tail regressed (-14us) -> 3-kernel
// tail restored. This round trims overhead only:
//  * k_lab fused into k_scatter prologue (scatter never reads lab; accum
//    reads it next kernel -> kernel-boundary visibility, no barrier).
//  * k_scan2 folded into k_final (each 1024-thr block redundantly wave-scans
//    bsums in LDS; deletes the serializing single-block dispatch).
// 4 dispatches + 2 memsets vs R7's 6 + 2.

#define KC1 6364136223846793005ULL
#define KC2 1442695040888963407ULL
#define KC3 2862933555777941757ULL
#define KC4 3202034522624059733ULL
#define KPT 1000003ULL

#define TBL_BITS 21
#define TBL (1u << TBL_BITS)
#define TMASK (TBL - 1u)
#define KEMPTY 0xFFFFFFFFFFFFFFFFULL
#define SIGMASK 0xFFFFFFFFFFF00000ULL   // high 44 bits = signature, low 20 = node idx

// binning: 4096 nodes per bucket (dl=12 bits, src=20 bits -> 32-bit record)
#define BK_SHIFT 12
#define BK_NODES 4096
#define NBK_MAX 256
// 8 block-partitions (blockIdx&7, write privacy) x 4 src-range partitions
// (accum gather window = 2MB of lab). cell = (bk << 2) | sp.
#define NPARTX 8
#define NPARTS 4
#define NPARTS_LOG 2
// per (part,cell) capacity: n=2M p=1/980 -> mean 2041, sigma ~45; ~4K total
// spills expected -> exact ovf path (verified absmax=0 in R3..R9).
#define PCAP 2132u
#define OVFCAP 32768u

// scatter tile: 16384 records staged in LDS, 16 records/thread in registers
#define TILE 16384
#define SUBP 4           // sub-passes of 4096 records (1024 thr x 4)

typedef int iv4 __attribute__((ext_vector_type(4)));

__device__ __forceinline__ uint64_t mix64(uint64_t h, uint64_t a, uint64_t b) {
    h *= a;
    h ^= (uint64_t)(((int64_t)h) >> 31);   // arithmetic shift, like jnp int64
    h *= b;
    h ^= (uint64_t)(((int64_t)h) >> 29);
    return h;
}

__device__ __forceinline__ uint32_t tslot(uint64_t k) {
    return (uint32_t)((k * 0x9E3779B97F4A7C15ULL) >> (64 - TBL_BITS));
}

// src-partition via magic-mul division: p = (src * M) >> 38, clamped.
__device__ __forceinline__ uint32_t psel(uint32_t src, uint32_t M) {
    uint32_t p = (uint32_t)(((uint64_t)src * (uint64_t)M) >> 38);
    return p < (NPARTS - 1) ? p : (NPARTS - 1);
}

// 2a. tile-sorted binning with fused lab-hash prologue.
//     Per 16K-edge tile: LDS hist -> wave-shfl scan -> per-cell global
//     reservation -> cell-sorted LDS stage -> coalesced flush.
//     Requires ncl = NPARTS*NBK <= 1024 (true for N <= 1,048,576).
__global__ __launch_bounds__(1024)
void k_scatter(const int* __restrict__ x, uint64_t* __restrict__ lab,
               const int* __restrict__ ei, uint32_t* __restrict__ binned,
               uint32_t* __restrict__ cursor, unsigned long long* __restrict__ ovf,
               unsigned int* __restrict__ ovf_cnt, int N, int F, int labChunk,
               int E, int NBK, int chunk, uint32_t M) {
    __shared__ uint32_t stageRec[TILE];                 // 64 KB
    __shared__ unsigned short stageCell[TILE];          // 32 KB
    __shared__ uint32_t hist[NPARTS * NBK_MAX];         // 4 KB
    __shared__ uint32_t cstart[NPARTS * NBK_MAX];       // 4 KB
    __shared__ uint32_t lbrun[NPARTS * NBK_MAX];        // 4 KB
    __shared__ uint32_t wsum[16];                       // -> ~108 KB total
    const int ncl = NPARTS * NBK;                       // 980; <= 1024 required
    const int part = blockIdx.x & (NPARTX - 1);
    const int tid = threadIdx.x;
    const int lane = tid & 63;
    const int wid = tid >> 6;

    // ---- 0. lab prologue: this block's node slice (read by NEXT kernel only)
    {
        const int nb0 = blockIdx.x * labChunk;
        const int nb1 = min(N, nb0 + labChunk);
        if (F == 8) {
            for (int n = nb0 + tid; n < nb1; n += 1024) {
                const iv4* p = (const iv4*)(x + (size_t)n * 8);
                iv4 a = p[0], b = p[1];
                uint64_t l = (uint64_t)(int64_t)a.x;
                l = l * KPT + (uint64_t)(int64_t)a.y;
                l = l * KPT + (uint64_t)(int64_t)a.z;
                l = l * KPT + (uint64_t)(int64_t)a.w;
                l = l * KPT + (uint64_t)(int64_t)b.x;
                l = l * KPT + (uint64_t)(int64_t)b.y;
                l = l * KPT + (uint64_t)(int64_t)b.z;
                l = l * KPT + (uint64_t)(int64_t)b.w;
                lab[n] = mix64(l, KC1, KC2);
            }
        } else {
            for (int n = nb0 + tid; n < nb1; n += 1024) {
                const int* row = x + (size_t)n * (size_t)F;
                uint64_t l = 0;
                for (int j = 0; j < F; ++j) l = l * KPT + (uint64_t)(int64_t)row[j];
                lab[n] = mix64(l, KC1, KC2);
            }
        }
    }

    const int b0 = blockIdx.x * chunk;
    const int b1 = min(E, b0 + chunk);
    if (b0 >= b1) return;

    if (tid < ncl) hist[tid] = 0;
    __syncthreads();

    for (int tb = b0; tb < b1; tb += TILE) {
        const int tE = min(TILE, b1 - tb);
        const int lim = min(b1, tb + TILE);
        // ---- 1. load up to 16 edges/thread (compile-time reg indices),
        //         count cells. meta = (cell<<14)|pos, sentinel ~0u.
        uint32_t rc[SUBP * 4];
        uint32_t meta[SUBP * 4];
#pragma unroll
        for (int sidx = 0; sidx < SUBP; ++sidx) {
            const int base = tb + sidx * 4096 + tid * 4;
            int ss[4], dd[4];
            int m = 0;
            if (base + 4 <= lim) {
                iv4 s4 = __builtin_nontemporal_load((const iv4*)(ei + base));
                iv4 d4 = __builtin_nontemporal_load((const iv4*)(ei + (size_t)E + base));
                ss[0]=s4.x; ss[1]=s4.y; ss[2]=s4.z; ss[3]=s4.w;
                dd[0]=d4.x; dd[1]=d4.y; dd[2]=d4.z; dd[3]=d4.w;
                m = 4;
            } else {
                int r = lim - base;
                m = r > 0 ? (r < 4 ? r : 4) : 0;
                for (int j = 0; j < m; ++j) {
                    ss[j] = ei[base + j];
                    dd[j] = ei[(size_t)E + base + j];
                }
            }
#pragma unroll
            for (int j = 0; j < 4; ++j) {
                const int k = sidx * 4 + j;
                if (j < m) {
                    uint32_t bk = (uint32_t)dd[j] >> BK_SHIFT;
                    uint32_t cell = (bk << NPARTS_LOG) | psel((uint32_t)ss[j], M);
                    uint32_t pos = atomicAdd(&hist[cell], 1u);
                    rc[k] = ((uint32_t)(dd[j] & (BK_NODES - 1)) << 20) | (uint32_t)ss[j];
                    meta[k] = (cell << 14) | pos;      // pos < 16384
                } else {
                    meta[k] = 0xFFFFFFFFu;
                }
            }
        }
        __syncthreads();
        // ---- 2. wave-shfl exclusive scan of hist (2 barriers, not 20)
        uint32_t v = (tid < ncl) ? hist[tid] : 0u;
        uint32_t s = v;
#pragma unroll
        for (int off = 1; off < 64; off <<= 1) {
            uint32_t t = __shfl_up(s, off, 64);
            if (lane >= off) s += t;
        }
        if (lane == 63) wsum[wid] = s;
        __syncthreads();
        if (wid == 0) {
            uint32_t w = (lane < 16) ? wsum[lane] : 0u;
#pragma unroll
            for (int off = 1; off < 16; off <<= 1) {
                uint32_t t = __shfl_up(w, off, 64);
                if (lane >= off) w += t;
            }
            if (lane < 16) wsum[lane] = w;   // inclusive scan of wave sums
        }
        __syncthreads();
        uint32_t incl = s + ((wid > 0) ? wsum[wid - 1] : 0u);
        // ---- 3. exclusive fixup + per-cell global reservation
        if (tid < ncl) {
            cstart[tid] = incl - v;
            lbrun[tid] = v ? atomicAdd(&cursor[part * ncl + tid], v) : 0u;
        }
        __syncthreads();
        // ---- 4. stage records sorted by cell
#pragma unroll
        for (int k = 0; k < SUBP * 4; ++k) {
            if (meta[k] != 0xFFFFFFFFu) {
                uint32_t cell = meta[k] >> 14;
                uint32_t p = cstart[cell] + (meta[k] & 0x3FFFu);
                stageRec[p] = rc[k];
                stageCell[p] = (unsigned short)cell;
            }
        }
        __syncthreads();
        // ---- 5. coalesced flush (lane-adjacent i -> contiguous per-cell runs)
        for (int i = tid; i < tE; i += 1024) {
            uint32_t rec = stageRec[i];
            uint32_t c = stageCell[i];
            uint32_t idx = lbrun[c] + ((uint32_t)i - cstart[c]);
            if (idx < PCAP) {
                binned[((size_t)part * ncl + c) * PCAP + idx] = rec;
            } else {
                unsigned int o = atomicAdd(ovf_cnt, 1u);
                if (o < OVFCAP) ovf[o] = ((unsigned long long)(c >> NPARTS_LOG) << 32) | rec;
            }
        }
        if (tid < ncl) hist[tid] = 0;   // ready for next tile
        __syncthreads();
    }
}

// 2b. per-bucket LDS multiset accumulation; sp-outer loop keeps the lab
//     gather window 2MB (L2-resident). ONE u64 LDS atomic/edge. R4/R7 loop
//     shape (fastest measured; per-CU line-fetch floor -- CLOSED, don't touch).
__global__ __launch_bounds__(1024)
void k_accum(const uint32_t* __restrict__ binned, const uint32_t* __restrict__ cursor,
             const unsigned long long* __restrict__ ovf, const unsigned int* __restrict__ ovf_cnt,
             const uint64_t* __restrict__ lab, unsigned long long* __restrict__ table,
             uint32_t* __restrict__ slot32, int N, int NBK) {
    __shared__ unsigned long long s1[BK_NODES];
    const int ncl = NPARTS * NBK;
    int b = blockIdx.x;
    for (int t = threadIdx.x; t < BK_NODES; t += blockDim.x) s1[t] = 0ULL;
    __syncthreads();
    for (int sp = 0; sp < NPARTS; ++sp) {
        const uint32_t cell = ((uint32_t)b << NPARTS_LOG) | (uint32_t)sp;
        for (int xp = 0; xp < NPARTX; ++xp) {
            size_t cidx = (size_t)xp * ncl + cell;
            uint32_t cnt = cursor[cidx];
            if (cnt > PCAP) cnt = PCAP;
            const uint32_t* seg = binned + cidx * PCAP;
            for (uint32_t i = threadIdx.x * 4; i < cnt; i += blockDim.x * 4) {
                uint32_t recs[4];
                int m;
                if (i + 4 <= cnt) {
                    iv4 r4 = __builtin_nontemporal_load((const iv4*)(seg + i));
                    recs[0]=(uint32_t)r4.x; recs[1]=(uint32_t)r4.y;
                    recs[2]=(uint32_t)r4.z; recs[3]=(uint32_t)r4.w;
                    m = 4;
                } else {
                    m = (int)(cnt - i);
                    for (int j = 0; j < m; ++j) recs[j] = seg[i + j];
                }
                for (int j = 0; j < m; ++j) {
                    uint64_t nl = lab[recs[j] & 0xFFFFFu];
                    uint32_t dl = recs[j] >> 20;
                    atomicAdd(&s1[dl], (unsigned long long)mix64(nl, KC1, KC2));
                }
            }
        }
    }
    // overflow sweep (expected ~4K records total; exact correctness backstop)
    uint32_t oc = *ovf_cnt;
    if (oc > OVFCAP) oc = OVFCAP;
    for (uint32_t i = threadIdx.x; i < oc; i += blockDim.x) {
        unsigned long long r = ovf[i];
        if ((uint32_t)(r >> 32) == (uint32_t)b) {
            uint32_t rec = (uint32_t)r;
            uint64_t nl = lab[rec & 0xFFFFFu];
            uint32_t dl = rec >> 20;
            atomicAdd(&s1[dl], (unsigned long long)mix64(nl, KC1, KC2));
        }
    }
    __syncthreads();
    int node0 = b << BK_SHIFT;
    for (int t = threadIdx.x; t < BK_NODES; t += blockDim.x) {
        int node = node0 + t;
        if (node < N) {
            uint64_t l = lab[node];
            uint64_t s = (uint64_t)s1[t];
            // commutative-multiset combine; induces the reference partition
            uint64_t h = mix64(l * KC3 + s, KC1, KC2) ^ mix64(s + l, KC3, KC4);
            // ---- fused insert: claim slot or min-merge into same-sig slot
            uint64_t entry = (h & SIGMASK) | (uint64_t)(uint32_t)node;
            uint32_t slot = tslot(h);
            for (;;) {
                unsigned long long cur = table[slot];
                if (cur == KEMPTY) {
                    unsigned long long prev =
                        atomicCAS(&table[slot], KEMPTY, (unsigned long long)entry);
                    if (prev == KEMPTY) break;
                    cur = prev;   // lost race: resolve with the true value
                }
                if ((cur & SIGMASK) == (entry & SIGMASK)) {
                    atomicMin(&table[slot], (unsigned long long)entry);
                    break;
                }
                slot = (slot + 1u) & TMASK;
            }
            slot32[node] = slot;
        }
    }
}

// 4b+4c fused: probe-free lookup (my memoized slot holds my group's min idx),
//     flag = (rep==i), wave shfl scan + 16-wave LDS combine (2 barriers).
__global__ __launch_bounds__(1024)
void k_lookup_scan(const uint32_t* __restrict__ slot32, const unsigned long long* __restrict__ table,
                   unsigned int* __restrict__ rep, int* __restrict__ incl,
                   int* __restrict__ bsums, int N) {
    __shared__ int wsum[16];
    int tid = threadIdx.x;
    int lane = tid & 63;
    int wid = tid >> 6;
    int i = blockIdx.x * 1024 + tid;
    int v = 0;
    if (i < N) {
        unsigned long long e = table[slot32[i]];
        unsigned int r = (unsigned int)(e & 0xFFFFFu);
        rep[i] = r;
        v = (r == (unsigned int)i) ? 1 : 0;
    }
    int s = v;
#pragma unroll
    for (int off = 1; off < 64; off <<= 1) {
        int t = __shfl_up(s, off, 64);
        if (lane >= off) s += t;
    }
    if (lane == 63) wsum[wid] = s;
    __syncthreads();
    if (wid == 0) {
        int w = (lane < 16) ? wsum[lane] : 0;
#pragma unroll
        for (int off = 1; off < 16; off <<= 1) {
            int t = __shfl_up(w, off, 64);
            if (lane >= off) w += t;
        }
        if (lane < 16) wsum[lane] = w;   // inclusive scan of wave sums
    }
    __syncthreads();
    int inclv = s + ((wid > 0) ? wsum[wid - 1] : 0);
    if (i < N) incl[i] = inclv;
    if (tid == 1023) bsums[blockIdx.x] = inclv;
}

// 5. final: each 1024-thr block wave-scans bsums (redundant, parallel) into
//    exclusive boffs in LDS, then out[i] = incl[rep[i]] + boffs[rep>>10] - 1.
__global__ __launch_bounds__(1024)
void k_final(const unsigned int* __restrict__ rep, const int* __restrict__ incl,
             const int* __restrict__ bsums, int* __restrict__ out, int N, int NB) {
    __shared__ int wsum[16];
    __shared__ int boffs[1024];
    int tid = threadIdx.x;
    int lane = tid & 63;
    int wid = tid >> 6;
    // block-local exclusive scan of bsums[0..NB)
    int v = (tid < NB) ? bsums[tid] : 0;
    int s = v;
#pragma unroll
    for (int off = 1; off < 64; off <<= 1) {
        int t = __shfl_up(s, off, 64);
        if (lane >= off) s += t;
    }
    if (lane == 63) wsum[wid] = s;
    __syncthreads();
    if (wid == 0) {
        int w = (lane < 16) ? wsum[lane] : 0;
#pragma unroll
        for (int off = 1; off < 16; off <<= 1) {
            int t = __shfl_up(w, off, 64);
            if (lane >= off) w += t;
        }
        if (lane < 16) wsum[lane] = w;
    }
    __syncthreads();
    boffs[tid] = s + ((wid > 0) ? wsum[wid - 1] : 0) - v;  // exclusive
    __syncthreads();
    int i = blockIdx.x * 1024 + tid;
    if (i < N) {
        unsigned int r = rep[i];
        out[i] = incl[r] + boffs[r >> 10] - 1;
    }
}

extern "C" void kernel_launch(void* const* d_in, const int* in_sizes, int n_in,
                              void* d_out, int out_size, void* d_ws, size_t ws_size,
                              hipStream_t stream) {
    const int* x  = (const int*)d_in[0];
    const int* ei = (const int*)d_in[1];
    int N = out_size;
    int F = in_sizes[0] / N;
    int E = in_sizes[1] / 2;
    int* out = (int*)d_out;

    int NBK = (N + BK_NODES - 1) >> BK_SHIFT;  // 245 for N=1e6
    uint32_t PSZ = (uint32_t)((N + NPARTS - 1) / NPARTS);         // 250000
    uint32_t M = (uint32_t)(((1ULL << 38) + PSZ - 1) / PSZ);      // magic for /PSZ

    // workspace layout; ~95.93 MB total (<= 96.03 MB proven)
    char* w = (char*)d_ws;
    uint64_t* lab = (uint64_t*)w;                        w += (size_t)N * 8;       // 8 MB
    uint32_t* slot32 = (uint32_t*)w;                     w += (size_t)N * 4;       // 4 MB
    uint32_t* cursor = (uint32_t*)w;                     w += (size_t)NPARTX * NPARTS * NBK_MAX * 4; // 32 KB
    unsigned int* ovf_cnt = (unsigned int*)w;            w += 16;
    unsigned long long* ovf = (unsigned long long*)w;    w += (size_t)OVFCAP * 8;  // 256 KB
    unsigned long long* table = (unsigned long long*)w;  w += (size_t)TBL * 8;     // 16 MB (live thru lookup)
    uint32_t* binned = (uint32_t*)w;                     // 8*980*PCAP*4 (~66.9 MB)
    // rep/incl/bsums dead until after k_accum -> alias the binned region
    char* a = (char*)binned;
    unsigned int* rep = (unsigned int*)a;                a += (size_t)N * 4;
    int* incl = (int*)a;                                 a += (size_t)N * 4;
    int* bsums = (int*)a;                                a += 1024 * 4;

    int NB = (N + 1023) / 1024;
    int SCB = 256;                                // 1 block/CU, part = blockIdx&7
    int chunk = ((E + SCB - 1) / SCB + 3) & ~3;   // 62500 for E=16M
    int labChunk = (N + SCB - 1) / SCB;           // 3907

    (void)hipMemsetAsync(cursor, 0, (size_t)NPARTX * NPARTS * NBK_MAX * 4 + 16, stream);
    (void)hipMemsetAsync(table, 0xFF, (size_t)TBL * 8, stream);
    k_scatter<<<SCB, 1024, 0, stream>>>(x, lab, ei, binned, cursor, ovf, ovf_cnt,
                                        N, F, labChunk, E, NBK, chunk, M);
    k_accum<<<NBK, 1024, 0, stream>>>(binned, cursor, ovf, ovf_cnt, lab, table, slot32, N, NBK);
    k_lookup_scan<<<NB, 1024, 0, stream>>>(slot32, table, rep, incl, bsums, N);
    k_final<<<NB, 1024, 0, stream>>>(rep, incl, bsums, out, N, NB);
}